// Round 8
// baseline (392.012 us; speedup 1.0000x reference)
//
#include <hip/hip_runtime.h>
#include <hip/hip_bf16.h>

// SelfAttention: B=4, S=2048, EMBED=1024, H=16, D=64
// Round 8: attn 2-deep software pipeline (T15): QK^T(t+1) overlaps
// softmax(t)+PV(t) within each wave. 3 rotating LDS buffer sets, ONE barrier
// per tile. Race audit: stage(t+2) -> [barrier] -> QK(t+2); PV(t-1) ->
// [barrier] -> stage(t+2). Pad 68 shorts (34 dw = 2 mod 32, 2-way free).
// Keeps: swapped QK^T, permuted-K staging, raw v_exp_f32, no row-max,
// XCD swizzle, setprio, zero-C first MFMA, dbuf out_gemm.

#define SS 2048
#define HH 16
#define DD 64

typedef __attribute__((ext_vector_type(8))) short bf16x8;
typedef __attribute__((ext_vector_type(4))) short s16x4;
typedef __attribute__((ext_vector_type(4))) float f32x4;
typedef __attribute__((ext_vector_type(16))) float f32x16;

__device__ __forceinline__ short f2bf(float f) {
  union { float f; unsigned u; } c; c.f = f;
  unsigned r = (c.u + 0x7FFFu + ((c.u >> 16) & 1u)) >> 16;  // RNE
  return (short)r;
}

__device__ __forceinline__ int cvtpk(float lo, float hi) {
  int r;
  asm("v_cvt_pk_bf16_f32 %0, %1, %2" : "=v"(r) : "v"(lo), "v"(hi));
  return r;
}

__device__ __forceinline__ float fexp2(float x) {
  float r;
  asm("v_exp_f32 %0, %1" : "=v"(r) : "v"(x));
  return r;
}

// ---------------------------------------------------------------- projections
__global__ __launch_bounds__(256) void proj_kernel(
    const float* __restrict__ xq, const float* __restrict__ xk, const float* __restrict__ xv,
    const float* __restrict__ Wq, const float* __restrict__ Wk, const float* __restrict__ Wv,
    short* __restrict__ qp, short* __restrict__ kp, short* __restrict__ vp)
{
  __shared__ short xlds[128][72];
  __shared__ short wlds[3][64][72];
  const int t = threadIdx.x;
  const int lane = t & 63;
  const int w = t >> 6;
  const int l15 = lane & 15, l4 = lane >> 4;

  const float* wsrc[3] = {Wq, Wk, Wv};
#pragma unroll
  for (int z = 0; z < 3; ++z) {
#pragma unroll
    for (int i = 0; i < 4; ++i) {
      int fi = (t + i * 256) * 4;
      int row = fi >> 6, col = fi & 63;
      float4 a = *(const float4*)(wsrc[z] + fi);
      s16x4 sv = { f2bf(a.x), f2bf(a.y), f2bf(a.z), f2bf(a.w) };
      *(s16x4*)&wlds[z][row][col] = sv;
    }
  }

  const long r0 = (long)blockIdx.x * 128;
  const float* xin[3] = {xq, xk, xv};
  short* outp[3] = {qp, kp, vp};
  const float SCQ = 0.03125f * 1.4426950408889634f;

#pragma unroll
  for (int z = 0; z < 3; ++z) {
    __syncthreads();
    const float* src = xin[z] + r0 * 64;
#pragma unroll
    for (int i = 0; i < 8; ++i) {
      int fi = (t + i * 256) * 4;
      int row = fi >> 6, col = fi & 63;
      float4 a = *(const float4*)(src + fi);
      s16x4 sv = { f2bf(a.x), f2bf(a.y), f2bf(a.z), f2bf(a.w) };
      *(s16x4*)&xlds[row][col] = sv;
    }
    __syncthreads();

    bf16x8 af[2][2];
#pragma unroll
    for (int mi = 0; mi < 2; ++mi)
#pragma unroll
      for (int kb = 0; kb < 2; ++kb)
        af[mi][kb] = *(const bf16x8*)&xlds[w * 32 + mi * 16 + l15][kb * 32 + l4 * 8];

    f32x4 acc[2][4];
#pragma unroll
    for (int mi = 0; mi < 2; ++mi)
#pragma unroll
      for (int nt = 0; nt < 4; ++nt)
        acc[mi][nt] = (f32x4){0.f, 0.f, 0.f, 0.f};

#pragma unroll
    for (int nt = 0; nt < 4; ++nt)
#pragma unroll
      for (int kb = 0; kb < 2; ++kb) {
        bf16x8 bfr = *(const bf16x8*)&wlds[z][nt * 16 + l15][kb * 32 + l4 * 8];
#pragma unroll
        for (int mi = 0; mi < 2; ++mi)
          acc[mi][nt] = __builtin_amdgcn_mfma_f32_16x16x32_bf16(af[mi][kb], bfr, acc[mi][nt], 0, 0, 0);
      }

    short* dst = outp[z];
    const float sc = (z == 0) ? SCQ : 1.0f;
#pragma unroll
    for (int mi = 0; mi < 2; ++mi)
#pragma unroll
      for (int nt = 0; nt < 4; ++nt)
#pragma unroll
        for (int j = 0; j < 4; ++j) {
          int r = (int)r0 + w * 32 + mi * 16 + l4 * 4 + j;   // (b*S+s)*16+h
          int e = nt * 16 + l15;
          int h = r & 15, bs = r >> 4;
          int b = bs >> 11, s = bs & 2047;
          dst[(((long)(b * 16 + h) * 2048 + s) << 6) + e] = f2bf(acc[mi][nt][j] * sc);
        }
  }
}

// ---------------------------------------------------------------- Wo -> bf16
__global__ __launch_bounds__(256) void wo_cvt(const float* __restrict__ Wo,
                                              short* __restrict__ wob) {
  long i = ((long)blockIdx.x * 256 + threadIdx.x) * 4;
  float4 a = *(const float4*)(Wo + i);
  s16x4 sv = { f2bf(a.x), f2bf(a.y), f2bf(a.z), f2bf(a.w) };
  *(s16x4*)(wob + i) = sv;
}

// ---------------------------------------------------------------- V transpose
__global__ __launch_bounds__(256) void vt_kernel(const short* __restrict__ vp,
                                                 short* __restrict__ vpt) {
  __shared__ short tl[64][72];
  const int t = threadIdx.x;
  const long base_in = (long)blockIdx.y * SS * DD + (long)blockIdx.x * 64 * DD;
#pragma unroll
  for (int i = 0; i < 2; ++i) {
    int c = t + i * 256;
    int s = c >> 3, d0 = (c & 7) * 8;
    bf16x8 v = *(const bf16x8*)(vp + base_in + s * 64 + d0);
#pragma unroll
    for (int j = 0; j < 8; ++j) tl[d0 + j][s] = v[j];
  }
  __syncthreads();
  const long base_out = (long)blockIdx.y * DD * SS + (long)blockIdx.x * 64;
#pragma unroll
  for (int i = 0; i < 2; ++i) {
    int c = t + i * 256;
    int d = c >> 3, s0 = (c & 7) * 8;
    *(bf16x8*)(vpt + base_out + (long)d * SS + s0) = *(const bf16x8*)&tl[d][s0];
  }
}

// ---------------------------------------------------------------- attention
#define LDW 68   // LDS row stride in shorts (34 dwords = 2 mod 32: 2-way, free)

#define QK_PHASE(SNXT, PKB) do {                                               \
  __builtin_amdgcn_s_setprio(1);                                               \
  _Pragma("unroll")                                                            \
  for (int kb_ = 0; kb_ < 2; ++kb_) {                                          \
    const short* kp_ = (PKB) + (kb_ * 32 + l31) * LDW;                         \
    bf16x8 ka0_ = *(const bf16x8*)(kp_ + hi * 8);                              \
    SNXT[kb_] = __builtin_amdgcn_mfma_f32_32x32x16_bf16(ka0_, qf[0], fzero, 0, 0, 0); \
    _Pragma("unroll")                                                          \
    for (int db_ = 1; db_ < 4; ++db_) {                                        \
      bf16x8 ka_ = *(const bf16x8*)(kp_ + db_ * 16 + hi * 8);                  \
      SNXT[kb_] = __builtin_amdgcn_mfma_f32_32x32x16_bf16(ka_, qf[db_], SNXT[kb_], 0, 0, 0); \
    }                                                                          \
  }                                                                            \
  __builtin_amdgcn_s_setprio(0);                                               \
} while (0)

#define STAGE_WR() do {                                                        \
  *(bf16x8*)(pkC + koff_w)     = kr0;                                          \
  *(bf16x8*)(pkC + koff_w + 8) = kr1;                                          \
  *(bf16x8*)(pvC + voff_w)     = vr0;                                          \
  *(bf16x8*)(pvC + voff_w + 8) = vr1;                                          \
} while (0)

#define PREFETCH(T3) do {                                                      \
  const long o_ = (long)(T3);                                                  \
  kr0 = *(const bf16x8*)(kr_ptr + o_ * 4096);                                  \
  kr1 = *(const bf16x8*)(kr_ptr + o_ * 4096 + 8);                              \
  vr0 = *(const bf16x8*)(vr_ptr + o_ * 64);                                    \
  vr1 = *(const bf16x8*)(vr_ptr + o_ * 64 + 8);                                \
} while (0)

#define SM_PV(T, SCUR, PVA) do {                                               \
  if (!tile_ok[(T)]) {                                                         \
    const int k0_ = (T) * 64;                                                  \
    _Pragma("unroll")                                                          \
    for (int kb_ = 0; kb_ < 2; ++kb_)                                          \
      _Pragma("unroll")                                                        \
      for (int r_ = 0; r_ < 16; ++r_) {                                        \
        int kv_ = k0_ + kb_ * 32 + 16 * ((r_ >> 3) & 1) + 8 * hi               \
                + 4 * ((r_ >> 2) & 1) + (r_ & 3);                              \
        if (mb[kv_] == 0) SCUR[kb_][r_] = -1e30f;                              \
      }                                                                        \
  }                                                                            \
  float s0_ = 0.f, s1_ = 0.f, s2_ = 0.f, s3_ = 0.f;                            \
  _Pragma("unroll")                                                            \
  for (int kb_ = 0; kb_ < 2; ++kb_)                                            \
    _Pragma("unroll")                                                          \
    for (int r_ = 0; r_ < 16; r_ += 4) {                                       \
      float p0_ = fexp2(SCUR[kb_][r_]);                                        \
      float p1_ = fexp2(SCUR[kb_][r_ + 1]);                                    \
      float p2_ = fexp2(SCUR[kb_][r_ + 2]);                                    \
      float p3_ = fexp2(SCUR[kb_][r_ + 3]);                                    \
      SCUR[kb_][r_] = p0_; SCUR[kb_][r_ + 1] = p1_;                            \
      SCUR[kb_][r_ + 2] = p2_; SCUR[kb_][r_ + 3] = p3_;                        \
      s0_ += p0_; s1_ += p1_; s2_ += p2_; s3_ += p3_;                          \
    }                                                                          \
  float sum_ = (s0_ + s1_) + (s2_ + s3_);                                      \
  sum_ += __shfl_xor(sum_, 32);                                                \
  l_reg += sum_;                                                               \
  union PW { int wd[4]; bf16x8 v; } pa_[4];                                    \
  _Pragma("unroll")                                                            \
  for (int kb_ = 0; kb_ < 2; ++kb_)                                            \
    _Pragma("unroll")                                                          \
    for (int s1i_ = 0; s1i_ < 2; ++s1i_)                                       \
      _Pragma("unroll")                                                        \
      for (int w2_ = 0; w2_ < 4; ++w2_)                                        \
        pa_[kb_ * 2 + s1i_].wd[w2_] =                                          \
            cvtpk(SCUR[kb_][8 * s1i_ + 2 * w2_], SCUR[kb_][8 * s1i_ + 2 * w2_ + 1]); \
  __builtin_amdgcn_s_setprio(1);                                               \
  _Pragma("unroll")                                                            \
  for (int dt_ = 0; dt_ < 2; ++dt_)                                            \
    _Pragma("unroll")                                                          \
    for (int ks_ = 0; ks_ < 4; ++ks_) {                                        \
      bf16x8 va_ = *(const bf16x8*)((PVA) + (dt_ * 32 + l31) * LDW + ks_ * 16 + hi * 8); \
      oacc[dt_] = __builtin_amdgcn_mfma_f32_32x32x16_bf16(va_, pa_[ks_].v, oacc[dt_], 0, 0, 0); \
    }                                                                          \
  __builtin_amdgcn_s_setprio(0);                                               \
} while (0)

#define ROT() do {                                                             \
  short* tp_ = pkA; pkA = pkB; pkB = pkC; pkC = tp_;                           \
  tp_ = pvA; pvA = pvB; pvB = pvC; pvC = tp_;                                  \
} while (0)

#define ITER(T, SCUR, SNXT) do {                                               \
  QK_PHASE(SNXT, pkB);                                                         \
  STAGE_WR();                                                                  \
  SM_PV((T), SCUR, pvA);                                                       \
  PREFETCH(((T) + 3 < 31) ? (T) + 3 : 31);                                     \
  __syncthreads();                                                             \
  ROT();                                                                       \
} while (0)

// grid 1024 (XCD-swizzled). 4 waves, 32 q-rows each.
__global__ __launch_bounds__(256, 3) void attn_kernel(
    const short* __restrict__ qp, const short* __restrict__ kp, const short* __restrict__ vpt,
    const int* __restrict__ mask, short* __restrict__ ao)
{
  __shared__ short kbuf[3][64][LDW];   // K tiles, rows permuted
  __shared__ short vbuf[3][64][LDW];   // V^T tiles [d][kv]
  __shared__ int tile_ok[32];
  const int t = threadIdx.x, lane = t & 63, w = t >> 6;
  const int l31 = lane & 31, hi = lane >> 5;
  const int wg = (blockIdx.x & 7) * 128 + (blockIdx.x >> 3);   // bijective XCD swizzle
  const int bh = wg >> 4, qt = wg & 15;
  const int b = bh >> 4, h = bh & 15;
  const short* qb  = qp + (long)bh * SS * DD;
  const short* kbp = kp + (long)bh * SS * DD;
  const short* vtp = vpt + (long)bh * DD * SS;
  const int* mb = mask + b * SS;

  if (t < 32) tile_ok[t] = 1;
  __syncthreads();
  {
    int ok = 1;
#pragma unroll
    for (int i = 0; i < 8; ++i) ok &= (mb[t * 8 + i] != 0);
    if (!ok) tile_ok[t >> 3] = 0;   // benign race: all writers store 0
  }

  const int q = qt * 128 + w * 32 + l31;
  bf16x8 qf[4];
#pragma unroll
  for (int dblk = 0; dblk < 4; ++dblk)
    qf[dblk] = *(const bf16x8*)(qb + (long)q * 64 + dblk * 16 + hi * 8);

  const int sr = t >> 2;                 // source kv / d row
  const int sc = (t & 3) * 16;
  const int v5 = sr & 31;                // permuted K row
  const int prow = (sr & 32) + (v5 & 3) + 4 * ((v5 >> 3) & 1)
                 + 8 * (2 * ((v5 >> 4) & 1) + ((v5 >> 2) & 1));
  const int koff_w = prow * LDW + sc;
  const int voff_w = sr * LDW + sc;
  const short* kr_ptr = kbp + (long)sr * 64 + sc;   // + t*4096 per tile
  const short* vr_ptr = vtp + (long)sr * SS + sc;   // + t*64 per tile

  short* pkA = &kbuf[0][0][0]; short* pkB = &kbuf[1][0][0]; short* pkC = &kbuf[2][0][0];
  short* pvA = &vbuf[0][0][0]; short* pvB = &vbuf[1][0][0]; short* pvC = &vbuf[2][0][0];

  const f32x16 fzero = {0.f,0.f,0.f,0.f,0.f,0.f,0.f,0.f,
                        0.f,0.f,0.f,0.f,0.f,0.f,0.f,0.f};
  f32x16 oacc[2];
  oacc[0] = fzero; oacc[1] = fzero;
  float l_reg = 0.f;
  bf16x8 kr0, kr1, vr0, vr1;

  // prologue: tiles 0,1 -> LDS; tile 2 -> regs; QK(0) -> sA
  PREFETCH(0);
  *(bf16x8*)(pkA + koff_w) = kr0; *(bf16x8*)(pkA + koff_w + 8) = kr1;
  *(bf16x8*)(pvA + voff_w) = vr0; *(bf16x8*)(pvA + voff_w + 8) = vr1;
  PREFETCH(1);
  *(bf16x8*)(pkB + koff_w) = kr0; *(bf16x8*)(pkB + koff_w + 8) = kr1;
  *(bf16x8*)(pvB + voff_w) = vr0; *(bf16x8*)(pvB + voff_w + 8) = vr1;
  PREFETCH(2);
  __syncthreads();

  f32x16 sA[2], sB[2];
  QK_PHASE(sA, pkA);

  for (int kt = 0; kt < 30; kt += 2) {
    ITER(kt, sA, sB);
    ITER(kt + 1, sB, sA);
  }
  ITER(30, sA, sB);
  // tail: tile 31 (pvA now = buf[31%3], holding tile 31's V)
  SM_PV(31, sB, pvA);

  float inv = 1.f / l_reg;
#pragma unroll
  for (int dt = 0; dt < 2; ++dt)
#pragma unroll
    for (int g = 0; g < 4; ++g) {
      s16x4 sv;
#pragma unroll
      for (int j = 0; j < 4; ++j) sv[j] = f2bf(oacc[dt][g * 4 + j] * inv);
      int d0 = dt * 32 + g * 8 + hi * 4;
      *(s16x4*)(ao + (long)(b * SS + q) * 1024 + h * 64 + d0) = sv;
    }
}

// ---------------------------------------------------------------- output GEMM
// Double-buffered, one barrier per K-step.
__global__ __launch_bounds__(256) void out_gemm(
    const short* __restrict__ ao, const short* __restrict__ wob,
    const float* __restrict__ bo, float* __restrict__ out)
{
  __shared__ short alds[2][128][72];
  __shared__ short blds[2][128][72];
  const int t = threadIdx.x, lane = t & 63, w = t >> 6;
  const int l15 = lane & 15, l4 = lane >> 4;
  const int wm = w >> 1, wn = w & 1;
  const long m0 = (long)blockIdx.y * 128;
  const int n0 = blockIdx.x * 128;

  const int srow = t >> 3;
  const int scol = (t & 7) * 8;

  f32x4 acc[4][4];
#pragma unroll
  for (int mi = 0; mi < 4; ++mi)
#pragma unroll
    for (int ni = 0; ni < 4; ++ni) acc[mi][ni] = (f32x4){0.f, 0.f, 0.f, 0.f};

  bf16x8 ar[4], br[4];
#pragma unroll
  for (int i = 0; i < 4; ++i) {
    int row = srow + i * 32;
    ar[i] = *(const bf16x8*)(ao + (m0 + row) * 1024 + scol);
    br[i] = *(const bf16x8*)(wob + (long)(n0 + row) * 1024 + scol);
  }
#pragma unroll
  for (int i = 0; i < 4; ++i) {
    int row = srow + i * 32;
    *(bf16x8*)&alds[0][row][scol] = ar[i];
    *(bf16x8*)&blds[0][row][scol] = br[i];
  }
#pragma unroll
  for (int i = 0; i < 4; ++i) {
    int row = srow + i * 32;
    ar[i] = *(const bf16x8*)(ao + (m0 + row) * 1024 + 64 + scol);
    br[i] = *(const bf16x8*)(wob + (long)(n0 + row) * 1024 + 64 + scol);
  }

  for (int ki = 0; ki < 16; ++ki) {
    const int cur = ki & 1, nxt = cur ^ 1;
    __syncthreads();
#pragma unroll
    for (int i = 0; i < 4; ++i) {
      int row = srow + i * 32;
      *(bf16x8*)&alds[nxt][row][scol] = ar[i];
      *(bf16x8*)&blds[nxt][row][scol] = br[i];
    }
#pragma unroll
    for (int kb = 0; kb < 2; ++kb) {
      bf16x8 af[4], bfr[4];
#pragma unroll
      for (int mi = 0; mi < 4; ++mi)
        af[mi] = *(const bf16x8*)&alds[cur][wm * 64 + mi * 16 + l15][kb * 32 + l4 * 8];
#pragma unroll
      for (int ni = 0; ni < 4; ++ni)
        bfr[ni] = *(const bf16x8*)&blds[cur][wn * 64 + ni * 16 + l15][kb * 32 + l4 * 8];
#pragma unroll
      for (int mi = 0; mi < 4; ++mi)
#pragma unroll
        for (int ni = 0; ni < 4; ++ni)
          acc[mi][ni] = __builtin_amdgcn_mfma_f32_16x16x32_bf16(af[mi], bfr[ni], acc[mi][ni], 0, 0, 0);
    }
    {
      const int kn = ((ki < 14) ? ki + 2 : 15) * 64;
#pragma unroll
      for (int i = 0; i < 4; ++i) {
        int row = srow + i * 32;
        ar[i] = *(const bf16x8*)(ao + (m0 + row) * 1024 + kn + scol);
        br[i] = *(const bf16x8*)(wob + (long)(n0 + row) * 1024 + kn + scol);
      }
    }
  }
#pragma unroll
  for (int ni = 0; ni < 4; ++ni) {
    float bias = bo[n0 + wn * 64 + ni * 16 + l15];
#pragma unroll
    for (int mi = 0; mi < 4; ++mi)
#pragma unroll
      for (int j = 0; j < 4; ++j)
        out[(m0 + wm * 64 + mi * 16 + l4 * 4 + j) * 1024 + n0 + wn * 64 + ni * 16 + l15] =
            acc[mi][ni][j] + bias;
  }
}

extern "C" void kernel_launch(void* const* d_in, const int* in_sizes, int n_in,
                              void* d_out, int out_size, void* d_ws, size_t ws_size,
                              hipStream_t stream) {
  const float* values = (const float*)d_in[0];
  const float* keys   = (const float*)d_in[1];
  const float* query  = (const float*)d_in[2];
  const int*   mask   = (const int*)d_in[3];
  const float* Wv     = (const float*)d_in[4];
  const float* Wk     = (const float*)d_in[5];
  const float* Wq     = (const float*)d_in[6];
  const float* Wo     = (const float*)d_in[7];
  const float* bo     = (const float*)d_in[8];
  float* out = (float*)d_out;

  const long NTOK = 4L * SS * HH * DD;      // 8388608
  short* qp  = (short*)d_ws;
  short* kp  = qp + NTOK;
  short* vp  = kp + NTOK;
  short* aot = vp + NTOK;
  short* wob = aot + NTOK;                  // 1 M shorts
  short* vpt = wob + 1024 * 1024;           // 8.4 M shorts

  hipLaunchKernelGGL(proj_kernel, dim3(1024), dim3(256), 0, stream,
                     query, keys, values, Wq, Wk, Wv, qp, kp, vp);
  hipLaunchKernelGGL(wo_cvt, dim3(1024), dim3(256), 0, stream, Wo, wob);
  hipLaunchKernelGGL(vt_kernel, dim3(32, 64), dim3(256), 0, stream, vp, vpt);
  hipLaunchKernelGGL(attn_kernel, dim3(1024), dim3(256), 0, stream,
                     qp, kp, vpt, mask, aot);
  hipLaunchKernelGGL(out_gemm, dim3(8, 64), dim3(256), 0, stream,
                     aot, wob, bo, out);
}

// Round 9
// 150.236 us; speedup vs baseline: 2.6093x; 2.6093x over previous
//
#include <hip/hip_runtime.h>
#include <hip/hip_bf16.h>

// SelfAttention: B=4, S=2048, EMBED=1024, H=16, D=64
// Round 9: r8's 2-deep pipeline REDONE with compile-time LDS buffer indices.
// r8's pointer-rotation (short* phi) broke addrspace inference -> flat_load/
// flat_store to LDS -> 4.4x regression (MfmaUtil 7.5%, all pipes idle).
// Fix: unroll main loop x6 (3 buffers x 2 sacc parity); every LDS access is
// kbuf[CONST][row][col] -> guaranteed ds_read/ds_write.
// Keeps: swapped QK^T, permuted-K staging, raw v_exp_f32, no row-max,
// XCD swizzle, setprio, zero-C first MFMA, dbuf out_gemm.

#define SS 2048
#define HH 16
#define DD 64

typedef __attribute__((ext_vector_type(8))) short bf16x8;
typedef __attribute__((ext_vector_type(4))) short s16x4;
typedef __attribute__((ext_vector_type(4))) float f32x4;
typedef __attribute__((ext_vector_type(16))) float f32x16;

__device__ __forceinline__ short f2bf(float f) {
  union { float f; unsigned u; } c; c.f = f;
  unsigned r = (c.u + 0x7FFFu + ((c.u >> 16) & 1u)) >> 16;  // RNE
  return (short)r;
}

__device__ __forceinline__ int cvtpk(float lo, float hi) {
  int r;
  asm("v_cvt_pk_bf16_f32 %0, %1, %2" : "=v"(r) : "v"(lo), "v"(hi));
  return r;
}

__device__ __forceinline__ float fexp2(float x) {
  float r;
  asm("v_exp_f32 %0, %1" : "=v"(r) : "v"(x));
  return r;
}

// ---------------------------------------------------------------- projections
__global__ __launch_bounds__(256) void proj_kernel(
    const float* __restrict__ xq, const float* __restrict__ xk, const float* __restrict__ xv,
    const float* __restrict__ Wq, const float* __restrict__ Wk, const float* __restrict__ Wv,
    short* __restrict__ qp, short* __restrict__ kp, short* __restrict__ vp)
{
  __shared__ short xlds[128][72];
  __shared__ short wlds[3][64][72];
  const int t = threadIdx.x;
  const int lane = t & 63;
  const int w = t >> 6;
  const int l15 = lane & 15, l4 = lane >> 4;

  const float* wsrc[3] = {Wq, Wk, Wv};
#pragma unroll
  for (int z = 0; z < 3; ++z) {
#pragma unroll
    for (int i = 0; i < 4; ++i) {
      int fi = (t + i * 256) * 4;
      int row = fi >> 6, col = fi & 63;
      float4 a = *(const float4*)(wsrc[z] + fi);
      s16x4 sv = { f2bf(a.x), f2bf(a.y), f2bf(a.z), f2bf(a.w) };
      *(s16x4*)&wlds[z][row][col] = sv;
    }
  }

  const long r0 = (long)blockIdx.x * 128;
  const float* xin[3] = {xq, xk, xv};
  short* outp[3] = {qp, kp, vp};
  const float SCQ = 0.03125f * 1.4426950408889634f;

#pragma unroll
  for (int z = 0; z < 3; ++z) {
    __syncthreads();
    const float* src = xin[z] + r0 * 64;
#pragma unroll
    for (int i = 0; i < 8; ++i) {
      int fi = (t + i * 256) * 4;
      int row = fi >> 6, col = fi & 63;
      float4 a = *(const float4*)(src + fi);
      s16x4 sv = { f2bf(a.x), f2bf(a.y), f2bf(a.z), f2bf(a.w) };
      *(s16x4*)&xlds[row][col] = sv;
    }
    __syncthreads();

    bf16x8 af[2][2];
#pragma unroll
    for (int mi = 0; mi < 2; ++mi)
#pragma unroll
      for (int kb = 0; kb < 2; ++kb)
        af[mi][kb] = *(const bf16x8*)&xlds[w * 32 + mi * 16 + l15][kb * 32 + l4 * 8];

    f32x4 acc[2][4];
#pragma unroll
    for (int mi = 0; mi < 2; ++mi)
#pragma unroll
      for (int nt = 0; nt < 4; ++nt)
        acc[mi][nt] = (f32x4){0.f, 0.f, 0.f, 0.f};

#pragma unroll
    for (int nt = 0; nt < 4; ++nt)
#pragma unroll
      for (int kb = 0; kb < 2; ++kb) {
        bf16x8 bfr = *(const bf16x8*)&wlds[z][nt * 16 + l15][kb * 32 + l4 * 8];
#pragma unroll
        for (int mi = 0; mi < 2; ++mi)
          acc[mi][nt] = __builtin_amdgcn_mfma_f32_16x16x32_bf16(af[mi][kb], bfr, acc[mi][nt], 0, 0, 0);
      }

    short* dst = outp[z];
    const float sc = (z == 0) ? SCQ : 1.0f;
#pragma unroll
    for (int mi = 0; mi < 2; ++mi)
#pragma unroll
      for (int nt = 0; nt < 4; ++nt)
#pragma unroll
        for (int j = 0; j < 4; ++j) {
          int r = (int)r0 + w * 32 + mi * 16 + l4 * 4 + j;   // (b*S+s)*16+h
          int e = nt * 16 + l15;
          int h = r & 15, bs = r >> 4;
          int b = bs >> 11, s = bs & 2047;
          dst[(((long)(b * 16 + h) * 2048 + s) << 6) + e] = f2bf(acc[mi][nt][j] * sc);
        }
  }
}

// ---------------------------------------------------------------- Wo -> bf16
__global__ __launch_bounds__(256) void wo_cvt(const float* __restrict__ Wo,
                                              short* __restrict__ wob) {
  long i = ((long)blockIdx.x * 256 + threadIdx.x) * 4;
  float4 a = *(const float4*)(Wo + i);
  s16x4 sv = { f2bf(a.x), f2bf(a.y), f2bf(a.z), f2bf(a.w) };
  *(s16x4*)(wob + i) = sv;
}

// ---------------------------------------------------------------- V transpose
__global__ __launch_bounds__(256) void vt_kernel(const short* __restrict__ vp,
                                                 short* __restrict__ vpt) {
  __shared__ short tl[64][72];
  const int t = threadIdx.x;
  const long base_in = (long)blockIdx.y * SS * DD + (long)blockIdx.x * 64 * DD;
#pragma unroll
  for (int i = 0; i < 2; ++i) {
    int c = t + i * 256;
    int s = c >> 3, d0 = (c & 7) * 8;
    bf16x8 v = *(const bf16x8*)(vp + base_in + s * 64 + d0);
#pragma unroll
    for (int j = 0; j < 8; ++j) tl[d0 + j][s] = v[j];
  }
  __syncthreads();
  const long base_out = (long)blockIdx.y * DD * SS + (long)blockIdx.x * 64;
#pragma unroll
  for (int i = 0; i < 2; ++i) {
    int c = t + i * 256;
    int d = c >> 3, s0 = (c & 7) * 8;
    *(bf16x8*)(vpt + base_out + (long)d * SS + s0) = *(const bf16x8*)&tl[d][s0];
  }
}

// ---------------------------------------------------------------- attention
#define LDW 68   // LDS row stride in shorts (34 dwords = 2 mod 32: 2-way, free)

#define QK_PHASE(SNXT, IB) do {                                                \
  __builtin_amdgcn_s_setprio(1);                                               \
  _Pragma("unroll")                                                            \
  for (int kb_ = 0; kb_ < 2; ++kb_) {                                          \
    bf16x8 ka0_ = *(const bf16x8*)&kbuf[IB][kb_ * 32 + l31][hi * 8];           \
    SNXT[kb_] = __builtin_amdgcn_mfma_f32_32x32x16_bf16(ka0_, qf[0], fzero, 0, 0, 0); \
    _Pragma("unroll")                                                          \
    for (int db_ = 1; db_ < 4; ++db_) {                                        \
      bf16x8 ka_ = *(const bf16x8*)&kbuf[IB][kb_ * 32 + l31][db_ * 16 + hi * 8]; \
      SNXT[kb_] = __builtin_amdgcn_mfma_f32_32x32x16_bf16(ka_, qf[db_], SNXT[kb_], 0, 0, 0); \
    }                                                                          \
  }                                                                            \
  __builtin_amdgcn_s_setprio(0);                                               \
} while (0)

#define STAGE_WR(IC) do {                                                      \
  *(bf16x8*)&kbuf[IC][prow][sc]     = kr0;                                     \
  *(bf16x8*)&kbuf[IC][prow][sc + 8] = kr1;                                     \
  *(bf16x8*)&vbuf[IC][sr][sc]       = vr0;                                     \
  *(bf16x8*)&vbuf[IC][sr][sc + 8]   = vr1;                                     \
} while (0)

#define PREFETCH(T3) do {                                                      \
  const long o_ = (long)(T3);                                                  \
  kr0 = *(const bf16x8*)(kr_ptr + o_ * 4096);                                  \
  kr1 = *(const bf16x8*)(kr_ptr + o_ * 4096 + 8);                              \
  vr0 = *(const bf16x8*)(vr_ptr + o_ * 64);                                    \
  vr1 = *(const bf16x8*)(vr_ptr + o_ * 64 + 8);                                \
} while (0)

#define SM_PV(T, SCUR, IA) do {                                                \
  if (!tile_ok[(T)]) {                                                         \
    const int k0_ = (T) * 64;                                                  \
    _Pragma("unroll")                                                          \
    for (int kb_ = 0; kb_ < 2; ++kb_)                                          \
      _Pragma("unroll")                                                        \
      for (int r_ = 0; r_ < 16; ++r_) {                                        \
        int kv_ = k0_ + kb_ * 32 + 16 * ((r_ >> 3) & 1) + 8 * hi               \
                + 4 * ((r_ >> 2) & 1) + (r_ & 3);                              \
        if (mb[kv_] == 0) SCUR[kb_][r_] = -1e30f;                              \
      }                                                                        \
  }                                                                            \
  float s0_ = 0.f, s1_ = 0.f, s2_ = 0.f, s3_ = 0.f;                            \
  _Pragma("unroll")                                                            \
  for (int kb_ = 0; kb_ < 2; ++kb_)                                            \
    _Pragma("unroll")                                                          \
    for (int r_ = 0; r_ < 16; r_ += 4) {                                       \
      float p0_ = fexp2(SCUR[kb_][r_]);                                        \
      float p1_ = fexp2(SCUR[kb_][r_ + 1]);                                    \
      float p2_ = fexp2(SCUR[kb_][r_ + 2]);                                    \
      float p3_ = fexp2(SCUR[kb_][r_ + 3]);                                    \
      SCUR[kb_][r_] = p0_; SCUR[kb_][r_ + 1] = p1_;                            \
      SCUR[kb_][r_ + 2] = p2_; SCUR[kb_][r_ + 3] = p3_;                        \
      s0_ += p0_; s1_ += p1_; s2_ += p2_; s3_ += p3_;                          \
    }                                                                          \
  float sum_ = (s0_ + s1_) + (s2_ + s3_);                                      \
  sum_ += __shfl_xor(sum_, 32);                                                \
  l_reg += sum_;                                                               \
  union PW { int wd[4]; bf16x8 v; } pa_[4];                                    \
  _Pragma("unroll")                                                            \
  for (int kb_ = 0; kb_ < 2; ++kb_)                                            \
    _Pragma("unroll")                                                          \
    for (int s1i_ = 0; s1i_ < 2; ++s1i_)                                       \
      _Pragma("unroll")                                                        \
      for (int w2_ = 0; w2_ < 4; ++w2_)                                        \
        pa_[kb_ * 2 + s1i_].wd[w2_] =                                          \
            cvtpk(SCUR[kb_][8 * s1i_ + 2 * w2_], SCUR[kb_][8 * s1i_ + 2 * w2_ + 1]); \
  __builtin_amdgcn_s_setprio(1);                                               \
  _Pragma("unroll")                                                            \
  for (int dt_ = 0; dt_ < 2; ++dt_)                                            \
    _Pragma("unroll")                                                          \
    for (int ks_ = 0; ks_ < 4; ++ks_) {                                        \
      bf16x8 va_ = *(const bf16x8*)&vbuf[IA][dt_ * 32 + l31][ks_ * 16 + hi * 8]; \
      oacc[dt_] = __builtin_amdgcn_mfma_f32_32x32x16_bf16(va_, pa_[ks_].v, oacc[dt_], 0, 0, 0); \
    }                                                                          \
  __builtin_amdgcn_s_setprio(0);                                               \
} while (0)

// One pipeline step: consume tile T (buf IA), QK tile T+1 (buf IB),
// stage tile T+2 (regs -> buf IC), prefetch tile T+3. IA/IB/IC are LITERALS.
#define ITER(T, SCUR, SNXT, IA, IB, IC) do {                                   \
  QK_PHASE(SNXT, IB);                                                          \
  STAGE_WR(IC);                                                                \
  SM_PV((T), SCUR, IA);                                                        \
  PREFETCH(((T) + 3 < 31) ? (T) + 3 : 31);                                     \
  __syncthreads();                                                             \
} while (0)

// grid 1024 (XCD-swizzled). 4 waves, 32 q-rows each.
__global__ __launch_bounds__(256, 3) void attn_kernel(
    const short* __restrict__ qp, const short* __restrict__ kp, const short* __restrict__ vpt,
    const int* __restrict__ mask, short* __restrict__ ao)
{
  __shared__ short kbuf[3][64][LDW];   // K tiles, rows permuted
  __shared__ short vbuf[3][64][LDW];   // V^T tiles [d][kv]
  __shared__ int tile_ok[32];
  const int t = threadIdx.x, lane = t & 63, w = t >> 6;
  const int l31 = lane & 31, hi = lane >> 5;
  const int wg = (blockIdx.x & 7) * 128 + (blockIdx.x >> 3);   // bijective XCD swizzle
  const int bh = wg >> 4, qt = wg & 15;
  const int b = bh >> 4, h = bh & 15;
  const short* qb  = qp + (long)bh * SS * DD;
  const short* kbp = kp + (long)bh * SS * DD;
  const short* vtp = vpt + (long)bh * DD * SS;
  const int* mb = mask + b * SS;

  if (t < 32) tile_ok[t] = 1;
  __syncthreads();
  {
    int ok = 1;
#pragma unroll
    for (int i = 0; i < 8; ++i) ok &= (mb[t * 8 + i] != 0);
    if (!ok) tile_ok[t >> 3] = 0;   // benign race: all writers store 0
  }

  const int q = qt * 128 + w * 32 + l31;
  bf16x8 qf[4];
#pragma unroll
  for (int dblk = 0; dblk < 4; ++dblk)
    qf[dblk] = *(const bf16x8*)(qb + (long)q * 64 + dblk * 16 + hi * 8);

  const int sr = t >> 2;                 // source kv / d row
  const int sc = (t & 3) * 16;
  const int v5 = sr & 31;                // permuted K row
  const int prow = (sr & 32) + (v5 & 3) + 4 * ((v5 >> 3) & 1)
                 + 8 * (2 * ((v5 >> 4) & 1) + ((v5 >> 2) & 1));
  const short* kr_ptr = kbp + (long)sr * 64 + sc;   // + T*4096 per tile
  const short* vr_ptr = vtp + (long)sr * SS + sc;   // + T*64 per tile

  const f32x16 fzero = {0.f,0.f,0.f,0.f,0.f,0.f,0.f,0.f,
                        0.f,0.f,0.f,0.f,0.f,0.f,0.f,0.f};
  f32x16 oacc[2];
  oacc[0] = fzero; oacc[1] = fzero;
  float l_reg = 0.f;
  bf16x8 kr0, kr1, vr0, vr1;

  // prologue: tile0 -> buf0, tile1 -> buf1, tile2 -> regs; QK(0) -> sA
  PREFETCH(0);
  STAGE_WR(0);
  PREFETCH(1);
  STAGE_WR(1);
  PREFETCH(2);
  __syncthreads();

  f32x16 sA[2], sB[2];
  QK_PHASE(sA, 0);

  // 6-step period: buffers rotate (0,1,2)->(1,2,0)->(2,0,1), sacc alternates
  for (int kt = 0; kt < 30; kt += 6) {
    ITER(kt + 0, sA, sB, 0, 1, 2);
    ITER(kt + 1, sB, sA, 1, 2, 0);
    ITER(kt + 2, sA, sB, 2, 0, 1);
    ITER(kt + 3, sB, sA, 0, 1, 2);
    ITER(kt + 4, sA, sB, 1, 2, 0);
    ITER(kt + 5, sB, sA, 2, 0, 1);
  }
  ITER(30, sA, sB, 0, 1, 2);
  // tail: tile 31's V sits in vbuf[1]
  SM_PV(31, sB, 1);

  float inv = 1.f / l_reg;
#pragma unroll
  for (int dt = 0; dt < 2; ++dt)
#pragma unroll
    for (int g = 0; g < 4; ++g) {
      s16x4 sv;
#pragma unroll
      for (int j = 0; j < 4; ++j) sv[j] = f2bf(oacc[dt][g * 4 + j] * inv);
      int d0 = dt * 32 + g * 8 + hi * 4;
      *(s16x4*)(ao + (long)(b * SS + q) * 1024 + h * 64 + d0) = sv;
    }
}

// ---------------------------------------------------------------- output GEMM
// Double-buffered, one barrier per K-step.
__global__ __launch_bounds__(256) void out_gemm(
    const short* __restrict__ ao, const short* __restrict__ wob,
    const float* __restrict__ bo, float* __restrict__ out)
{
  __shared__ short alds[2][128][72];
  __shared__ short blds[2][128][72];
  const int t = threadIdx.x, lane = t & 63, w = t >> 6;
  const int l15 = lane & 15, l4 = lane >> 4;
  const int wm = w >> 1, wn = w & 1;
  const long m0 = (long)blockIdx.y * 128;
  const int n0 = blockIdx.x * 128;

  const int srow = t >> 3;
  const int scol = (t & 7) * 8;

  f32x4 acc[4][4];
#pragma unroll
  for (int mi = 0; mi < 4; ++mi)
#pragma unroll
    for (int ni = 0; ni < 4; ++ni) acc[mi][ni] = (f32x4){0.f, 0.f, 0.f, 0.f};

  bf16x8 ar[4], br[4];
#pragma unroll
  for (int i = 0; i < 4; ++i) {
    int row = srow + i * 32;
    ar[i] = *(const bf16x8*)(ao + (m0 + row) * 1024 + scol);
    br[i] = *(const bf16x8*)(wob + (long)(n0 + row) * 1024 + scol);
  }
#pragma unroll
  for (int i = 0; i < 4; ++i) {
    int row = srow + i * 32;
    *(bf16x8*)&alds[0][row][scol] = ar[i];
    *(bf16x8*)&blds[0][row][scol] = br[i];
  }
#pragma unroll
  for (int i = 0; i < 4; ++i) {
    int row = srow + i * 32;
    ar[i] = *(const bf16x8*)(ao + (m0 + row) * 1024 + 64 + scol);
    br[i] = *(const bf16x8*)(wob + (long)(n0 + row) * 1024 + 64 + scol);
  }

  for (int ki = 0; ki < 16; ++ki) {
    const int cur = ki & 1, nxt = cur ^ 1;
    __syncthreads();
#pragma unroll
    for (int i = 0; i < 4; ++i) {
      int row = srow + i * 32;
      *(bf16x8*)&alds[nxt][row][scol] = ar[i];
      *(bf16x8*)&blds[nxt][row][scol] = br[i];
    }
#pragma unroll
    for (int kb = 0; kb < 2; ++kb) {
      bf16x8 af[4], bfr[4];
#pragma unroll
      for (int mi = 0; mi < 4; ++mi)
        af[mi] = *(const bf16x8*)&alds[cur][wm * 64 + mi * 16 + l15][kb * 32 + l4 * 8];
#pragma unroll
      for (int ni = 0; ni < 4; ++ni)
        bfr[ni] = *(const bf16x8*)&blds[cur][wn * 64 + ni * 16 + l15][kb * 32 + l4 * 8];
#pragma unroll
      for (int mi = 0; mi < 4; ++mi)
#pragma unroll
        for (int ni = 0; ni < 4; ++ni)
          acc[mi][ni] = __builtin_amdgcn_mfma_f32_16x16x32_bf16(af[mi], bfr[ni], acc[mi][ni], 0, 0, 0);
    }
    {
      const int kn = ((ki < 14) ? ki + 2 : 15) * 64;
#pragma unroll
      for (int i = 0; i < 4; ++i) {
        int row = srow + i * 32;
        ar[i] = *(const bf16x8*)(ao + (m0 + row) * 1024 + kn + scol);
        br[i] = *(const bf16x8*)(wob + (long)(n0 + row) * 1024 + kn + scol);
      }
    }
  }
#pragma unroll
  for (int ni = 0; ni < 4; ++ni) {
    float bias = bo[n0 + wn * 64 + ni * 16 + l15];
#pragma unroll
    for (int mi = 0; mi < 4; ++mi)
#pragma unroll
      for (int j = 0; j < 4; ++j)
        out[(m0 + wm * 64 + mi * 16 + l4 * 4 + j) * 1024 + n0 + wn * 64 + ni * 16 + l15] =
            acc[mi][ni][j] + bias;
  }
}

extern "C" void kernel_launch(void* const* d_in, const int* in_sizes, int n_in,
                              void* d_out, int out_size, void* d_ws, size_t ws_size,
                              hipStream_t stream) {
  const float* values = (const float*)d_in[0];
  const float* keys   = (const float*)d_in[1];
  const float* query  = (const float*)d_in[2];
  const int*   mask   = (const int*)d_in[3];
  const float* Wv     = (const float*)d_in[4];
  const float* Wk     = (const float*)d_in[5];
  const float* Wq     = (const float*)d_in[6];
  const float* Wo     = (const float*)d_in[7];
  const float* bo     = (const float*)d_in[8];
  float* out = (float*)d_out;

  const long NTOK = 4L * SS * HH * DD;      // 8388608
  short* qp  = (short*)d_ws;
  short* kp  = qp + NTOK;
  short* vp  = kp + NTOK;
  short* aot = vp + NTOK;
  short* wob = aot + NTOK;                  // 1 M shorts
  short* vpt = wob + 1024 * 1024;           // 8.4 M shorts

  hipLaunchKernelGGL(proj_kernel, dim3(1024), dim3(256), 0, stream,
                     query, keys, values, Wq, Wk, Wv, qp, kp, vp);
  hipLaunchKernelGGL(wo_cvt, dim3(1024), dim3(256), 0, stream, Wo, wob);
  hipLaunchKernelGGL(vt_kernel, dim3(32, 64), dim3(256), 0, stream, vp, vpt);
  hipLaunchKernelGGL(attn_kernel, dim3(1024), dim3(256), 0, stream,
                     qp, kp, vpt, mask, aot);
  hipLaunchKernelGGL(out_gemm, dim3(8, 64), dim3(256), 0, stream,
                     aot, wob, bo, out);
}